// Round 14
// baseline (4762.623 us; speedup 1.0000x reference)
//
#include <hip/hip_runtime.h>
#include <hip/hip_bf16.h>
#include <math.h>

#define E   512
#define E3  1536
#define NH  8
#define FF  32
#define NL  3
#define NV  32000
#define NB  128
#define NT  16
#define RESCUE_DELTA 0.08f

typedef __attribute__((ext_vector_type(8))) short bf16x8;
typedef __attribute__((ext_vector_type(4))) float f32x4;

// ---------------- setup: pe table (blocks 0..15) + tok row 0 (blocks 16..143)
__global__ void setup_kernel(float* __restrict__ pe, float* __restrict__ tb,
                             const float* __restrict__ emb) {
    const int bi = blockIdx.x;
    if (bi < 16) {
        for (int e = threadIdx.x; e < E; e += blockDim.x) {
            int k = e >> 1;
            double dv = exp((double)(2 * k) * (-log(10000.0) / (double)E));
            double arg = (double)bi * dv;
            pe[bi * E + e] = (e & 1) ? (float)cos(arg) : (float)sin(arg);
        }
    } else {
        const int b = bi - 16;
        for (int e = threadIdx.x; e < E; e += blockDim.x)
            tb[(size_t)b * E + e] = emb[(size_t)1 * E + e];  // SOS = 1
    }
}

// ---------------- fp32 -> bf16 (RNE) bulk convert; n % 1024 == 0
__global__ __launch_bounds__(256) void cvt_bf16_kernel(
    const float* __restrict__ src, unsigned short* __restrict__ dst)
{
    const int i = (blockIdx.x * 256 + threadIdx.x) * 4;
    const float4 v = *(const float4*)&src[i];
    __hip_bfloat16 h0 = __float2bfloat16(v.x);
    __hip_bfloat16 h1 = __float2bfloat16(v.y);
    __hip_bfloat16 h2 = __float2bfloat16(v.z);
    __hip_bfloat16 h3 = __float2bfloat16(v.w);
    dst[i + 0] = *(unsigned short*)&h0;
    dst[i + 1] = *(unsigned short*)&h1;
    dst[i + 2] = *(unsigned short*)&h2;
    dst[i + 3] = *(unsigned short*)&h3;
}

// ---- cross-attn constant: ca_const[l][b] = ((cur_room @ Wv^T + bv) @ Wout^T + bout)
__global__ __launch_bounds__(256) void ca_setup_kernel(
    const float* __restrict__ cur_room,
    const float* __restrict__ ca_in_w, const float* __restrict__ ca_in_b,
    const float* __restrict__ ca_out_w, const float* __restrict__ ca_out_b,
    float* __restrict__ ca_const)
{
    const int b = blockIdx.x, l = blockIdx.y, t = threadIdx.x;
    __shared__ float xl[E];
    __shared__ float hv[E];
    for (int e = t; e < E; e += 256) xl[e] = cur_room[(size_t)b * E + e];
    __syncthreads();
    const float* wv = ca_in_w + ((size_t)l * E3 + 2 * E) * E;
    const float* bv = ca_in_b + (size_t)l * E3 + 2 * E;
    for (int c = t; c < E; c += 256) {
        float s = bv[c];
        const float* wr = wv + (size_t)c * E;
        for (int k = 0; k < E; ++k) s += xl[k] * wr[k];
        hv[c] = s;
    }
    __syncthreads();
    const float* wo = ca_out_w + (size_t)l * E * E;
    for (int c = t; c < E; c += 256) {
        float s = ca_out_b[(size_t)l * E + c];
        const float* wr = wo + (size_t)c * E;
        for (int k = 0; k < E; ++k) s += hv[k] * wr[k];
        ca_const[((size_t)l * NB + b) * E + c] = s;
    }
}

// ---------------------------------------------------------------- GEMM v3
template<bool ADD_BIAS>
__global__ __launch_bounds__(256) void gemm_v3_kernel(
    const float* __restrict__ A, const float* __restrict__ W,
    const float* __restrict__ bias, float* __restrict__ C,
    int N, int K, int KC, size_t CS, int skipm)
{
    const int m0 = blockIdx.y * 64;
    const int n0 = blockIdx.x * 128;
    if (n0 < E && m0 < skipm) return;
    __shared__ float As[16][68];
    __shared__ float Bs[16][132];
    const int tid = threadIdx.x;
    const int kc0 = blockIdx.z * KC;
    const int tx = tid & 15;
    const int ty = tid >> 4;
    const int sr = tid >> 2;
    const int sc = (tid & 3) * 4;

    const float* Ap  = A + (size_t)(m0 + sr) * K + kc0 + sc;
    const float* Wp0 = W + (size_t)(n0 + sr) * K + kc0 + sc;
    const float* Wp1 = W + (size_t)(n0 + 64 + sr) * K + kc0 + sc;

    float4 pa  = *(const float4*)Ap;
    float4 pb0 = *(const float4*)Wp0;
    float4 pb1 = *(const float4*)Wp1;

    float acc[4][8] = {};
    const int nkt = KC >> 4;
    for (int kt = 0; kt < nkt; ++kt) {
        __syncthreads();
        As[sc + 0][sr] = pa.x;  As[sc + 1][sr] = pa.y;
        As[sc + 2][sr] = pa.z;  As[sc + 3][sr] = pa.w;
        Bs[sc + 0][sr] = pb0.x; Bs[sc + 1][sr] = pb0.y;
        Bs[sc + 2][sr] = pb0.z; Bs[sc + 3][sr] = pb0.w;
        Bs[sc + 0][64 + sr] = pb1.x; Bs[sc + 1][64 + sr] = pb1.y;
        Bs[sc + 2][64 + sr] = pb1.z; Bs[sc + 3][64 + sr] = pb1.w;
        __syncthreads();
        if (kt + 1 < nkt) {
            const int off = 16 * (kt + 1);
            pa  = *(const float4*)(Ap + off);
            pb0 = *(const float4*)(Wp0 + off);
            pb1 = *(const float4*)(Wp1 + off);
        }
#pragma unroll
        for (int k = 0; k < 16; ++k) {
            float a[4], b[8];
            *(float4*)&a[0] = *(const float4*)&As[k][ty * 4];
            *(float4*)&b[0] = *(const float4*)&Bs[k][tx * 4];
            *(float4*)&b[4] = *(const float4*)&Bs[k][64 + tx * 4];
#pragma unroll
            for (int i = 0; i < 4; ++i)
#pragma unroll
                for (int j = 0; j < 8; ++j)
                    acc[i][j] += a[i] * b[j];
        }
    }
    float* Co = C + (size_t)blockIdx.z * CS;
#pragma unroll
    for (int i = 0; i < 4; ++i) {
        const int m = m0 + ty * 4 + i;
#pragma unroll
        for (int cj = 0; cj < 2; ++cj) {
            const int n = n0 + cj * 64 + tx * 4;
            float4 o;
            o.x = acc[i][cj * 4 + 0];
            o.y = acc[i][cj * 4 + 1];
            o.z = acc[i][cj * 4 + 2];
            o.w = acc[i][cj * 4 + 3];
            if (ADD_BIAS) {
                const float4 bv = *(const float4*)&bias[n];
                o.x += bv.x; o.y += bv.y; o.z += bv.z; o.w += bv.w;
            }
            *(float4*)&Co[(size_t)m * N + n] = o;
        }
    }
}

// ------------------------------------------- bf16 MFMA vocab projection
__global__ __launch_bounds__(256) void vgemm_bf16_kernel(
    const unsigned short* __restrict__ Abf,
    const unsigned short* __restrict__ Wbf,
    const float* __restrict__ bias, float* __restrict__ Cout)
{
    const int wid = threadIdx.x >> 6, lane = threadIdx.x & 63;
    const int n0 = (blockIdx.x * 4 + wid) * 32;
    const int r = lane & 15;
    const int ko = (lane >> 4) * 8;
    f32x4 acc[2][8];
#pragma unroll
    for (int nt = 0; nt < 2; ++nt)
#pragma unroll
        for (int m = 0; m < 8; ++m)
            acc[nt][m] = (f32x4){0.f, 0.f, 0.f, 0.f};

    const unsigned short* a0 = Abf + (size_t)r * E + ko;
    const unsigned short* w0 = Wbf + (size_t)(n0 + r) * E + ko;
    const unsigned short* w1 = Wbf + (size_t)(n0 + 16 + r) * E + ko;
    for (int k0 = 0; k0 < E; k0 += 32) {
        const bf16x8 b0 = *(const bf16x8*)(w0 + k0);
        const bf16x8 b1 = *(const bf16x8*)(w1 + k0);
#pragma unroll
        for (int m = 0; m < 8; ++m) {
            const bf16x8 af = *(const bf16x8*)(a0 + (size_t)m * 16 * E + k0);
            acc[0][m] = __builtin_amdgcn_mfma_f32_16x16x32_bf16(af, b0, acc[0][m], 0, 0, 0);
            acc[1][m] = __builtin_amdgcn_mfma_f32_16x16x32_bf16(af, b1, acc[1][m], 0, 0, 0);
        }
    }
    const int crow = (lane >> 4) * 4;
#pragma unroll
    for (int nt = 0; nt < 2; ++nt) {
        const int col = n0 + nt * 16 + r;
        const float bv = bias[col];
#pragma unroll
        for (int m = 0; m < 8; ++m)
#pragma unroll
            for (int rr = 0; rr < 4; ++rr)
                Cout[(size_t)(m * 16 + crow + rr) * NV + col] = acc[nt][m][rr] + bv;
    }
}

// -------------------------------------------------------- self attention
// 256 threads (4 waves): staging rounds halved, query loop spread 4-wide.
template<bool WB>
__global__ __launch_bounds__(256) void attn_kernel(
    const float* __restrict__ qkv, size_t QS, int pcount,
    const float* __restrict__ cache, float* __restrict__ wbdst,
    const float* __restrict__ bias,
    float* __restrict__ o, int S, int qstart)
{
    const int b = blockIdx.x >> 3;
    const int h = blockIdx.x & 7;
    __shared__ float Ks[16][64];
    __shared__ float Vs[16][64];
    const int tid = threadIdx.x;
    if (WB) {
        for (int e = tid; e < 192; e += 256) {
            const int part = e >> 6, d = e & 63;
            const int go = part * E + h * 64 + d;
            float v = 0.f;
#pragma unroll
            for (int p = 0; p < 8; ++p) v += qkv[(size_t)p * QS + (size_t)b * E3 + go];
            wbdst[(size_t)b * E3 + go] = v;
            if (part == 1) Ks[S - 1][d] = v + bias[go];
            else if (part == 2) Vs[S - 1][d] = v + bias[go];
        }
        for (int idx = tid; idx < (S - 1) * 64; idx += 256) {
            const int s = idx >> 6, d = idx & 63;
            const size_t base = ((size_t)(s * NB + b)) * E3 + h * 64 + d;
            Ks[s][d] = cache[base + E] + bias[E + h * 64 + d];
            Vs[s][d] = cache[base + 2 * E] + bias[2 * E + h * 64 + d];
        }
    } else {
        for (int idx = tid; idx < S * 64; idx += 256) {
            const int s = idx >> 6, d = idx & 63;
            const size_t base = ((size_t)(s * NB + b)) * E3 + h * 64 + d;
            float kk = bias[E + h * 64 + d];
            float vv = bias[2 * E + h * 64 + d];
            for (int p = 0; p < pcount; ++p) {
                kk += qkv[(size_t)p * QS + base + E];
                vv += qkv[(size_t)p * QS + base + 2 * E];
            }
            Ks[s][d] = kk;
            Vs[s][d] = vv;
        }
    }
    __syncthreads();
    const int wid = tid >> 6, lane = tid & 63;
    const float bq = bias[h * 64 + lane];
    for (int qi = qstart + wid; qi < S; qi += 4) {
        const size_t qbase = ((size_t)(qi * NB + b)) * E3 + h * 64 + lane;
        float qd = bq;
        if (WB) qd += cache[qbase];
        else for (int p = 0; p < pcount; ++p) qd += qkv[(size_t)p * QS + qbase];
        float sc[16];
#pragma unroll
        for (int ki = 0; ki < 16; ++ki) {
            float p = 0.f;
            if (ki < S) {
                p = qd * Ks[ki][lane];
#pragma unroll
                for (int off = 32; off; off >>= 1) p += __shfl_xor(p, off);
                p *= 0.125f;
            }
            sc[ki] = p;
        }
        float m = -1e30f;
#pragma unroll
        for (int ki = 0; ki < 16; ++ki) if (ki < S) m = fmaxf(m, sc[ki]);
        float sum = 0.f;
#pragma unroll
        for (int ki = 0; ki < 16; ++ki) if (ki < S) { sc[ki] = expf(sc[ki] - m); sum += sc[ki]; }
        float inv = 1.0f / sum;
        float acc = 0.f;
#pragma unroll
        for (int ki = 0; ki < 16; ++ki) if (ki < S) acc += sc[ki] * Vs[ki][lane];
        o[((size_t)(qi * NB + b)) * E + h * 64 + lane] = acc * inv;
    }
}

// ---- fused epilogue; optionally also emits bf16 copy of output rows (xbf)
__global__ __launch_bounds__(256) void epilogue_kernel(
    const float* __restrict__ xin,
    const float* __restrict__ yp, size_t YS, int pcount,
    const float* __restrict__ ob,
    const float* __restrict__ ca,
    const float* __restrict__ g0, const float* __restrict__ b0,
    const float* __restrict__ g1, const float* __restrict__ b1,
    const float* __restrict__ w1, const float* __restrict__ b1f,
    const float* __restrict__ w2, const float* __restrict__ b2f,
    const float* __restrict__ g2, const float* __restrict__ bb2,
    float* __restrict__ xout, unsigned short* __restrict__ xbf, int rows)
{
    const int wid = threadIdx.x >> 6, lane = threadIdx.x & 63;
    const int row = blockIdx.x * 4 + wid;
    if (row >= rows) return;
    const float* xr = xin + (size_t)row * E;
    const float* cr = ca + (size_t)(row & (NB - 1)) * E;
    float v[8];
    float s = 0.f;
#pragma unroll
    for (int j = 0; j < 8; ++j) {
        int e = j * 64 + lane;
        float y = xr[e] + ob[e];
        for (int p = 0; p < pcount; ++p) y += yp[(size_t)p * YS + (size_t)row * E + e];
        v[j] = y; s += y;
    }
#pragma unroll
    for (int off = 32; off; off >>= 1) s += __shfl_xor(s, off);
    float mean = s * (1.0f / E);
    float vs = 0.f;
#pragma unroll
    for (int j = 0; j < 8; ++j) { float d = v[j] - mean; vs += d * d; }
#pragma unroll
    for (int off = 32; off; off >>= 1) vs += __shfl_xor(vs, off);
    float rstd = rsqrtf(vs * (1.0f / E) + 1e-5f);
#pragma unroll
    for (int j = 0; j < 8; ++j) {
        int e = j * 64 + lane;
        v[j] = (v[j] - mean) * rstd * g0[e] + b0[e] + cr[e];
    }
    s = 0.f;
#pragma unroll
    for (int j = 0; j < 8; ++j) s += v[j];
#pragma unroll
    for (int off = 32; off; off >>= 1) s += __shfl_xor(s, off);
    mean = s * (1.0f / E);
    vs = 0.f;
#pragma unroll
    for (int j = 0; j < 8; ++j) { float d = v[j] - mean; vs += d * d; }
#pragma unroll
    for (int off = 32; off; off >>= 1) vs += __shfl_xor(vs, off);
    rstd = rsqrtf(vs * (1.0f / E) + 1e-5f);
#pragma unroll
    for (int j = 0; j < 8; ++j) {
        int e = j * 64 + lane;
        v[j] = (v[j] - mean) * rstd * g1[e] + b1[e];
    }
    float h[FF];
#pragma unroll
    for (int f = 0; f < FF; ++f) {
        float p = 0.f;
#pragma unroll
        for (int j = 0; j < 8; ++j) p += v[j] * w1[(size_t)f * E + j * 64 + lane];
#pragma unroll
        for (int off = 32; off; off >>= 1) p += __shfl_xor(p, off);
        h[f] = fmaxf(p + b1f[f], 0.f);
    }
    float o[8];
#pragma unroll
    for (int j = 0; j < 8; ++j) {
        int e = j * 64 + lane;
        float acc = b2f[e];
#pragma unroll
        for (int f4 = 0; f4 < FF / 4; ++f4) {
            float4 w4 = *(const float4*)&w2[(size_t)e * FF + f4 * 4];
            acc += h[f4 * 4 + 0] * w4.x + h[f4 * 4 + 1] * w4.y +
                   h[f4 * 4 + 2] * w4.z + h[f4 * 4 + 3] * w4.w;
        }
        o[j] = v[j] + acc;
    }
    s = 0.f;
#pragma unroll
    for (int j = 0; j < 8; ++j) s += o[j];
#pragma unroll
    for (int off = 32; off; off >>= 1) s += __shfl_xor(s, off);
    mean = s * (1.0f / E);
    vs = 0.f;
#pragma unroll
    for (int j = 0; j < 8; ++j) { float d = o[j] - mean; vs += d * d; }
#pragma unroll
    for (int off = 32; off; off >>= 1) vs += __shfl_xor(vs, off);
    rstd = rsqrtf(vs * (1.0f / E) + 1e-5f);
#pragma unroll
    for (int j = 0; j < 8; ++j) {
        int e = j * 64 + lane;
        const float val = (o[j] - mean) * rstd * g2[e] + bb2[e];
        xout[(size_t)row * E + e] = val;
        if (xbf) {
            __hip_bfloat16 hb = __float2bfloat16(val);
            xbf[(size_t)row * E + e] = *(unsigned short*)&hb;
        }
    }
}

// ------- softmax v3: bf16 logits + exact-fp32 argmax rescue
__global__ __launch_bounds__(1024) void softmax_v3_kernel(
    const float* __restrict__ logits,
    const float* __restrict__ xrow,
    const float* __restrict__ out_w,
    const float* __restrict__ ob,
    float* __restrict__ probs_out, float* __restrict__ tok_out,
    const float* __restrict__ emb, const float* __restrict__ pe_row,
    float* __restrict__ tb_new, int step)
{
    const int b = blockIdx.x, t = threadIdx.x;
    const int wid = t >> 6, lane = t & 63;
    const float* L = logits + (size_t)b * NV;
    float r[32];
    float vmax = -1e30f;
#pragma unroll
    for (int j = 0; j < 32; ++j) {
        const int idx = j * 1024 + t;
        if (idx < NV) { r[j] = L[idx]; vmax = fmaxf(vmax, r[j]); }
        else r[j] = -1e30f;
    }
#pragma unroll
    for (int off = 32; off; off >>= 1) vmax = fmaxf(vmax, __shfl_xor(vmax, off));
    __shared__ float swv[16];
    __shared__ float ssum[16];
    __shared__ float sbc[2];
    __shared__ int scnt;
    __shared__ int cand[64];
    __shared__ float cex[64];
    __shared__ int stok;
    if (lane == 0) swv[wid] = vmax;
    if (t == 0) scnt = 0;
    __syncthreads();
    if (t == 0) {
        float m = swv[0];
        for (int w = 1; w < 16; ++w) m = fmaxf(m, swv[w]);
        sbc[0] = m;
    }
    __syncthreads();
    const float m = sbc[0];
#pragma unroll
    for (int j = 0; j < 32; ++j) {
        const int idx = j * 1024 + t;
        if (idx < NV && r[j] >= m - RESCUE_DELTA) {
            const int p = atomicAdd(&scnt, 1);
            if (p < 64) cand[p] = idx;
        }
    }
    __syncthreads();
    const int nc = min(scnt, 64);
    const float* xr = xrow + (size_t)b * E;
    for (int c = wid; c < nc; c += 16) {
        const float* wr = out_w + (size_t)cand[c] * E;
        const float4 a0 = *(const float4*)&xr[lane * 8];
        const float4 a1 = *(const float4*)&xr[lane * 8 + 4];
        const float4 w0 = *(const float4*)&wr[lane * 8];
        const float4 w1 = *(const float4*)&wr[lane * 8 + 4];
        float s = a0.x * w0.x + a0.y * w0.y + a0.z * w0.z + a0.w * w0.w +
                  a1.x * w1.x + a1.y * w1.y + a1.z * w1.z + a1.w * w1.w;
#pragma unroll
        for (int off = 32; off; off >>= 1) s += __shfl_xor(s, off);
        if (lane == 0) cex[c] = s + ob[cand[c]];
    }
    __syncthreads();
    if (t == 0) {
        float bv = -1e30f; int bi = 0x7fffffff;
        for (int c = 0; c < nc; ++c) {
            const float v = cex[c]; const int ii = cand[c];
            if (v > bv || (v == bv && ii < bi)) { bv = v; bi = ii; }
        }
        stok = bi;
    }
    float psum = 0.f;
#pragma unroll
    for (int j = 0; j < 32; ++j) {
        const int idx = j * 1024 + t;
        if (idx < NV) { r[j] = expf(r[j] - m); psum += r[j]; }
    }
#pragma unroll
    for (int off = 32; off; off >>= 1) psum += __shfl_xor(psum, off);
    if (lane == 0) ssum[wid] = psum;
    __syncthreads();
    if (t == 0) {
        float s = 0.f;
        for (int w = 0; w < 16; ++w) s += ssum[w];
        sbc[1] = 1.0f / s;
    }
    __syncthreads();
    const float inv = sbc[1];
    const int tok = stok;
    float* P = probs_out + (size_t)b * NV;
#pragma unroll
    for (int j = 0; j < 32; ++j) {
        const int idx = j * 1024 + t;
        if (idx < NV) P[idx] = r[j] * inv;
    }
    if (t == 0) tok_out[(size_t)b * NT + step] = (float)tok;
    if (t < E) tb_new[(size_t)b * E + t] = emb[(size_t)tok * E + t] + pe_row[t];
}

// ================================================================ host
extern "C" void kernel_launch(void* const* d_in, const int* in_sizes, int n_in,
                              void* d_out, int out_size, void* d_ws, size_t ws_size,
                              hipStream_t stream) {
    const float* cur_room = (const float*)d_in[0];
    const float* emb      = (const float*)d_in[1];
    const float* sa_in_w  = (const float*)d_in[2];
    const float* sa_in_b  = (const float*)d_in[3];
    const float* sa_out_w = (const float*)d_in[4];
    const float* sa_out_b = (const float*)d_in[5];
    const float* ca_in_w  = (const float*)d_in[6];
    const float* ca_in_b  = (const float*)d_in[7];
    const float* ca_out_w = (const float*)d_in[8];
    const float* ca_out_b = (const float*)d_in[9];
    const float* ff1_w    = (const float*)d_in[10];
    const float* ff1_b    = (const float*)d_in[11];
    const float* ff2_w    = (const float*)d_in[12];
    const float* ff2_b    = (const float*)d_in[13];
    const float* ln_g     = (const float*)d_in[14];
    const float* ln_b     = (const float*)d_in[15];
    const float* out_w    = (const float*)d_in[16];
    const float* out_b    = (const float*)d_in[17];
    float* out = (float*)d_out;

    float* ws = (float*)d_ws;
    float* pe       = ws;
    float* ca_const = pe + 16 * E;
    float* tokb     = ca_const + (size_t)NL * NB * E;
    float* x        = tokb + (size_t)17 * NB * E;
    float* qkv0p    = x + (size_t)NT * NB * E;
    float* qkv0     = qkv0p + (size_t)8 * NB * E3;
    float* qkvp     = qkv0 + (size_t)NT * NB * E3;
    float* attn_o   = qkvp + (size_t)32 * NB * E3;
    float* ypart    = attn_o + (size_t)NT * NB * E;
    float* vocp     = ypart + (size_t)4718592;
    unsigned short* wbf = (unsigned short*)(vocp + (size_t)NB * NV);
    unsigned short* xbf = wbf + (size_t)NV * E;

    setup_kernel<<<144, 256, 0, stream>>>(pe, tokb, emb);
    ca_setup_kernel<<<dim3(NB, NL), 256, 0, stream>>>(
        cur_room, ca_in_w, ca_in_b, ca_out_w, ca_out_b, ca_const);
    cvt_bf16_kernel<<<(NV * E) / 1024, 256, 0, stream>>>(out_w, wbf);

    const size_t QS0 = (size_t)NB * E3;

    for (int i = 0; i < NT; ++i) {
        const int S = i + 1;
        const int M = S * NB;
        const size_t QSM = (size_t)M * E3;
        const size_t YSM = (size_t)M * E;

        // ---- layer 0: incremental qkv (new 128 rows), split-K=8; attn combines
        gemm_v3_kernel<false><<<dim3(E3 / 128, 2, 8), 256, 0, stream>>>(
            tokb + (size_t)i * NB * E, sa_in_w, nullptr, qkv0p, E3, E, 64, QS0, 0);

        const int z_out = (S <= 4) ? 8 : 4;
        // qkv split-K: unsplit at large S (264+ blocks without it; attention
        // staging traffic halves when pcount drops 2 -> 1)
        const int z_qkv = (S <= 2) ? 8 : (S <= 6) ? 4 : (S <= 10) ? 2 : 1;
        for (int l = 0; l < NL; ++l) {
            const float* xin = (l == 0) ? tokb : x;
            const int skipm = (l == 2) ? (S - 1) * NB : 0;
            const int qstart = (l == 2) ? S - 1 : 0;

            if (l == 0) {
                attn_kernel<true><<<NB * NH, 256, 0, stream>>>(
                    qkv0p, QS0, 8, qkv0, qkv0 + (size_t)i * NB * E3,
                    sa_in_b, attn_o, S, 0);
            } else {
                gemm_v3_kernel<false><<<dim3(E3 / 128, 2 * S, z_qkv), 256, 0, stream>>>(
                    x, sa_in_w + (size_t)l * E3 * E, nullptr, qkvp, E3, E, E / z_qkv,
                    QSM, skipm);
                attn_kernel<false><<<NB * NH, 256, 0, stream>>>(
                    qkvp, QSM, z_qkv, nullptr, nullptr,
                    sa_in_b + (size_t)l * E3, attn_o, S, qstart);
            }

            if (l == 2) {
                gemm_v3_kernel<false><<<dim3(E / 128, 2, 8), 256, 0, stream>>>(
                    attn_o + (size_t)(S - 1) * NB * E, sa_out_w + (size_t)l * E * E,
                    nullptr, ypart, E, E, 64, (size_t)NB * E, 0);
                epilogue_kernel<<<32, 256, 0, stream>>>(
                    xin + (size_t)(S - 1) * NB * E, ypart, (size_t)NB * E, 8,
                    sa_out_b + (size_t)l * E, ca_const + (size_t)l * NB * E,
                    ln_g + (size_t)(l * 3 + 0) * E, ln_b + (size_t)(l * 3 + 0) * E,
                    ln_g + (size_t)(l * 3 + 1) * E, ln_b + (size_t)(l * 3 + 1) * E,
                    ff1_w + (size_t)l * FF * E, ff1_b + (size_t)l * FF,
                    ff2_w + (size_t)l * E * FF, ff2_b + (size_t)l * E,
                    ln_g + (size_t)(l * 3 + 2) * E, ln_b + (size_t)(l * 3 + 2) * E,
                    x + (size_t)(S - 1) * NB * E, xbf, NB);
            } else {
                gemm_v3_kernel<false><<<dim3(E / 128, 2 * S, z_out), 256, 0, stream>>>(
                    attn_o, sa_out_w + (size_t)l * E * E, nullptr,
                    ypart, E, E, E / z_out, YSM, 0);
                epilogue_kernel<<<S * 32, 256, 0, stream>>>(
                    xin, ypart, YSM, z_out,
                    sa_out_b + (size_t)l * E, ca_const + (size_t)l * NB * E,
                    ln_g + (size_t)(l * 3 + 0) * E, ln_b + (size_t)(l * 3 + 0) * E,
                    ln_g + (size_t)(l * 3 + 1) * E, ln_b + (size_t)(l * 3 + 1) * E,
                    ff1_w + (size_t)l * FF * E, ff1_b + (size_t)l * FF,
                    ff2_w + (size_t)l * E * FF, ff2_b + (size_t)l * E,
                    ln_g + (size_t)(l * 3 + 2) * E, ln_b + (size_t)(l * 3 + 2) * E,
                    x, nullptr, M);
            }
        }
        // ---- vocab: bf16 MFMA logits + softmax with exact-fp32 argmax rescue
        vgemm_bf16_kernel<<<NV / 128, 256, 0, stream>>>(xbf, wbf, out_b, vocp);
        softmax_v3_kernel<<<NB, 1024, 0, stream>>>(
            vocp, x + (size_t)i * NB * E, out_w, out_b,
            out + 2048 + (size_t)i * NB * NV, out,
            emb, pe + (size_t)i * E, tokb + (size_t)S * NB * E, i);
    }
}

// Round 15
// 4625.663 us; speedup vs baseline: 1.0296x; 1.0296x over previous
//
#include <hip/hip_runtime.h>
#include <hip/hip_bf16.h>
#include <math.h>

#define E   512
#define E3  1536
#define NH  8
#define FF  32
#define NL  3
#define NV  32000
#define NB  128
#define NT  16
#define RESCUE_DELTA 0.08f

typedef __attribute__((ext_vector_type(8))) short bf16x8;
typedef __attribute__((ext_vector_type(4))) float f32x4;

// ---------------- setup: pe table (blocks 0..15) + tok row 0 (blocks 16..143)
__global__ void setup_kernel(float* __restrict__ pe, float* __restrict__ tb,
                             const float* __restrict__ emb) {
    const int bi = blockIdx.x;
    if (bi < 16) {
        for (int e = threadIdx.x; e < E; e += blockDim.x) {
            int k = e >> 1;
            double dv = exp((double)(2 * k) * (-log(10000.0) / (double)E));
            double arg = (double)bi * dv;
            pe[bi * E + e] = (e & 1) ? (float)cos(arg) : (float)sin(arg);
        }
    } else {
        const int b = bi - 16;
        for (int e = threadIdx.x; e < E; e += blockDim.x)
            tb[(size_t)b * E + e] = emb[(size_t)1 * E + e];  // SOS = 1
    }
}

// ---------------- fp32 -> bf16 (RNE) bulk convert; n % 1024 == 0
__global__ __launch_bounds__(256) void cvt_bf16_kernel(
    const float* __restrict__ src, unsigned short* __restrict__ dst)
{
    const int i = (blockIdx.x * 256 + threadIdx.x) * 4;
    const float4 v = *(const float4*)&src[i];
    __hip_bfloat16 h0 = __float2bfloat16(v.x);
    __hip_bfloat16 h1 = __float2bfloat16(v.y);
    __hip_bfloat16 h2 = __float2bfloat16(v.z);
    __hip_bfloat16 h3 = __float2bfloat16(v.w);
    dst[i + 0] = *(unsigned short*)&h0;
    dst[i + 1] = *(unsigned short*)&h1;
    dst[i + 2] = *(unsigned short*)&h2;
    dst[i + 3] = *(unsigned short*)&h3;
}

// ---- cross-attn constant: ca_const[l][b] = ((cur_room @ Wv^T + bv) @ Wout^T + bout)
__global__ __launch_bounds__(256) void ca_setup_kernel(
    const float* __restrict__ cur_room,
    const float* __restrict__ ca_in_w, const float* __restrict__ ca_in_b,
    const float* __restrict__ ca_out_w, const float* __restrict__ ca_out_b,
    float* __restrict__ ca_const)
{
    const int b = blockIdx.x, l = blockIdx.y, t = threadIdx.x;
    __shared__ float xl[E];
    __shared__ float hv[E];
    for (int e = t; e < E; e += 256) xl[e] = cur_room[(size_t)b * E + e];
    __syncthreads();
    const float* wv = ca_in_w + ((size_t)l * E3 + 2 * E) * E;
    const float* bv = ca_in_b + (size_t)l * E3 + 2 * E;
    for (int c = t; c < E; c += 256) {
        float s = bv[c];
        const float* wr = wv + (size_t)c * E;
        for (int k = 0; k < E; ++k) s += xl[k] * wr[k];
        hv[c] = s;
    }
    __syncthreads();
    const float* wo = ca_out_w + (size_t)l * E * E;
    for (int c = t; c < E; c += 256) {
        float s = ca_out_b[(size_t)l * E + c];
        const float* wr = wo + (size_t)c * E;
        for (int k = 0; k < E; ++k) s += hv[k] * wr[k];
        ca_const[((size_t)l * NB + b) * E + c] = s;
    }
}

// ---------------------------------------------------------------- GEMM v3
template<bool ADD_BIAS>
__global__ __launch_bounds__(256) void gemm_v3_kernel(
    const float* __restrict__ A, const float* __restrict__ W,
    const float* __restrict__ bias, float* __restrict__ C,
    int N, int K, int KC, size_t CS, int skipm)
{
    const int m0 = blockIdx.y * 64;
    const int n0 = blockIdx.x * 128;
    if (n0 < E && m0 < skipm) return;
    __shared__ float As[16][68];
    __shared__ float Bs[16][132];
    const int tid = threadIdx.x;
    const int kc0 = blockIdx.z * KC;
    const int tx = tid & 15;
    const int ty = tid >> 4;
    const int sr = tid >> 2;
    const int sc = (tid & 3) * 4;

    const float* Ap  = A + (size_t)(m0 + sr) * K + kc0 + sc;
    const float* Wp0 = W + (size_t)(n0 + sr) * K + kc0 + sc;
    const float* Wp1 = W + (size_t)(n0 + 64 + sr) * K + kc0 + sc;

    float4 pa  = *(const float4*)Ap;
    float4 pb0 = *(const float4*)Wp0;
    float4 pb1 = *(const float4*)Wp1;

    float acc[4][8] = {};
    const int nkt = KC >> 4;
    for (int kt = 0; kt < nkt; ++kt) {
        __syncthreads();
        As[sc + 0][sr] = pa.x;  As[sc + 1][sr] = pa.y;
        As[sc + 2][sr] = pa.z;  As[sc + 3][sr] = pa.w;
        Bs[sc + 0][sr] = pb0.x; Bs[sc + 1][sr] = pb0.y;
        Bs[sc + 2][sr] = pb0.z; Bs[sc + 3][sr] = pb0.w;
        Bs[sc + 0][64 + sr] = pb1.x; Bs[sc + 1][64 + sr] = pb1.y;
        Bs[sc + 2][64 + sr] = pb1.z; Bs[sc + 3][64 + sr] = pb1.w;
        __syncthreads();
        if (kt + 1 < nkt) {
            const int off = 16 * (kt + 1);
            pa  = *(const float4*)(Ap + off);
            pb0 = *(const float4*)(Wp0 + off);
            pb1 = *(const float4*)(Wp1 + off);
        }
#pragma unroll
        for (int k = 0; k < 16; ++k) {
            float a[4], b[8];
            *(float4*)&a[0] = *(const float4*)&As[k][ty * 4];
            *(float4*)&b[0] = *(const float4*)&Bs[k][tx * 4];
            *(float4*)&b[4] = *(const float4*)&Bs[k][64 + tx * 4];
#pragma unroll
            for (int i = 0; i < 4; ++i)
#pragma unroll
                for (int j = 0; j < 8; ++j)
                    acc[i][j] += a[i] * b[j];
        }
    }
    float* Co = C + (size_t)blockIdx.z * CS;
#pragma unroll
    for (int i = 0; i < 4; ++i) {
        const int m = m0 + ty * 4 + i;
#pragma unroll
        for (int cj = 0; cj < 2; ++cj) {
            const int n = n0 + cj * 64 + tx * 4;
            float4 o;
            o.x = acc[i][cj * 4 + 0];
            o.y = acc[i][cj * 4 + 1];
            o.z = acc[i][cj * 4 + 2];
            o.w = acc[i][cj * 4 + 3];
            if (ADD_BIAS) {
                const float4 bv = *(const float4*)&bias[n];
                o.x += bv.x; o.y += bv.y; o.z += bv.z; o.w += bv.w;
            }
            *(float4*)&Co[(size_t)m * N + n] = o;
        }
    }
}

// ------------------------------------------- bf16 MFMA vocab projection
__global__ __launch_bounds__(256) void vgemm_bf16_kernel(
    const unsigned short* __restrict__ Abf,
    const unsigned short* __restrict__ Wbf,
    const float* __restrict__ bias, float* __restrict__ Cout)
{
    const int wid = threadIdx.x >> 6, lane = threadIdx.x & 63;
    const int n0 = (blockIdx.x * 4 + wid) * 32;
    const int r = lane & 15;
    const int ko = (lane >> 4) * 8;
    f32x4 acc[2][8];
#pragma unroll
    for (int nt = 0; nt < 2; ++nt)
#pragma unroll
        for (int m = 0; m < 8; ++m)
            acc[nt][m] = (f32x4){0.f, 0.f, 0.f, 0.f};

    const unsigned short* a0 = Abf + (size_t)r * E + ko;
    const unsigned short* w0 = Wbf + (size_t)(n0 + r) * E + ko;
    const unsigned short* w1 = Wbf + (size_t)(n0 + 16 + r) * E + ko;
    for (int k0 = 0; k0 < E; k0 += 32) {
        const bf16x8 b0 = *(const bf16x8*)(w0 + k0);
        const bf16x8 b1 = *(const bf16x8*)(w1 + k0);
#pragma unroll
        for (int m = 0; m < 8; ++m) {
            const bf16x8 af = *(const bf16x8*)(a0 + (size_t)m * 16 * E + k0);
            acc[0][m] = __builtin_amdgcn_mfma_f32_16x16x32_bf16(af, b0, acc[0][m], 0, 0, 0);
            acc[1][m] = __builtin_amdgcn_mfma_f32_16x16x32_bf16(af, b1, acc[1][m], 0, 0, 0);
        }
    }
    const int crow = (lane >> 4) * 4;
#pragma unroll
    for (int nt = 0; nt < 2; ++nt) {
        const int col = n0 + nt * 16 + r;
        const float bv = bias[col];
#pragma unroll
        for (int m = 0; m < 8; ++m)
#pragma unroll
            for (int rr = 0; rr < 4; ++rr)
                Cout[(size_t)(m * 16 + crow + rr) * NV + col] = acc[nt][m][rr] + bv;
    }
}

// -------------------------------------------------------- self attention
// 256 threads (4 waves): staging rounds halved, query loop spread 4-wide.
template<bool WB>
__global__ __launch_bounds__(256) void attn_kernel(
    const float* __restrict__ qkv, size_t QS, int pcount,
    const float* __restrict__ cache, float* __restrict__ wbdst,
    const float* __restrict__ bias,
    float* __restrict__ o, int S, int qstart)
{
    const int b = blockIdx.x >> 3;
    const int h = blockIdx.x & 7;
    __shared__ float Ks[16][64];
    __shared__ float Vs[16][64];
    const int tid = threadIdx.x;
    if (WB) {
        for (int e = tid; e < 192; e += 256) {
            const int part = e >> 6, d = e & 63;
            const int go = part * E + h * 64 + d;
            float v = 0.f;
#pragma unroll
            for (int p = 0; p < 8; ++p) v += qkv[(size_t)p * QS + (size_t)b * E3 + go];
            wbdst[(size_t)b * E3 + go] = v;
            if (part == 1) Ks[S - 1][d] = v + bias[go];
            else if (part == 2) Vs[S - 1][d] = v + bias[go];
        }
        for (int idx = tid; idx < (S - 1) * 64; idx += 256) {
            const int s = idx >> 6, d = idx & 63;
            const size_t base = ((size_t)(s * NB + b)) * E3 + h * 64 + d;
            Ks[s][d] = cache[base + E] + bias[E + h * 64 + d];
            Vs[s][d] = cache[base + 2 * E] + bias[2 * E + h * 64 + d];
        }
    } else {
        for (int idx = tid; idx < S * 64; idx += 256) {
            const int s = idx >> 6, d = idx & 63;
            const size_t base = ((size_t)(s * NB + b)) * E3 + h * 64 + d;
            float kk = bias[E + h * 64 + d];
            float vv = bias[2 * E + h * 64 + d];
            for (int p = 0; p < pcount; ++p) {
                kk += qkv[(size_t)p * QS + base + E];
                vv += qkv[(size_t)p * QS + base + 2 * E];
            }
            Ks[s][d] = kk;
            Vs[s][d] = vv;
        }
    }
    __syncthreads();
    const int wid = tid >> 6, lane = tid & 63;
    const float bq = bias[h * 64 + lane];
    for (int qi = qstart + wid; qi < S; qi += 4) {
        const size_t qbase = ((size_t)(qi * NB + b)) * E3 + h * 64 + lane;
        float qd = bq;
        if (WB) qd += cache[qbase];
        else for (int p = 0; p < pcount; ++p) qd += qkv[(size_t)p * QS + qbase];
        float sc[16];
#pragma unroll
        for (int ki = 0; ki < 16; ++ki) {
            float p = 0.f;
            if (ki < S) {
                p = qd * Ks[ki][lane];
#pragma unroll
                for (int off = 32; off; off >>= 1) p += __shfl_xor(p, off);
                p *= 0.125f;
            }
            sc[ki] = p;
        }
        float m = -1e30f;
#pragma unroll
        for (int ki = 0; ki < 16; ++ki) if (ki < S) m = fmaxf(m, sc[ki]);
        float sum = 0.f;
#pragma unroll
        for (int ki = 0; ki < 16; ++ki) if (ki < S) { sc[ki] = expf(sc[ki] - m); sum += sc[ki]; }
        float inv = 1.0f / sum;
        float acc = 0.f;
#pragma unroll
        for (int ki = 0; ki < 16; ++ki) if (ki < S) acc += sc[ki] * Vs[ki][lane];
        o[((size_t)(qi * NB + b)) * E + h * 64 + lane] = acc * inv;
    }
}

// ---- fused epilogue; optionally also emits bf16 copy of output rows (xbf)
__global__ __launch_bounds__(256) void epilogue_kernel(
    const float* __restrict__ xin,
    const float* __restrict__ yp, size_t YS, int pcount,
    const float* __restrict__ ob,
    const float* __restrict__ ca,
    const float* __restrict__ g0, const float* __restrict__ b0,
    const float* __restrict__ g1, const float* __restrict__ b1,
    const float* __restrict__ w1, const float* __restrict__ b1f,
    const float* __restrict__ w2, const float* __restrict__ b2f,
    const float* __restrict__ g2, const float* __restrict__ bb2,
    float* __restrict__ xout, unsigned short* __restrict__ xbf, int rows)
{
    const int wid = threadIdx.x >> 6, lane = threadIdx.x & 63;
    const int row = blockIdx.x * 4 + wid;
    if (row >= rows) return;
    const float* xr = xin + (size_t)row * E;
    const float* cr = ca + (size_t)(row & (NB - 1)) * E;
    float v[8];
    float s = 0.f;
#pragma unroll
    for (int j = 0; j < 8; ++j) {
        int e = j * 64 + lane;
        float y = xr[e] + ob[e];
        for (int p = 0; p < pcount; ++p) y += yp[(size_t)p * YS + (size_t)row * E + e];
        v[j] = y; s += y;
    }
#pragma unroll
    for (int off = 32; off; off >>= 1) s += __shfl_xor(s, off);
    float mean = s * (1.0f / E);
    float vs = 0.f;
#pragma unroll
    for (int j = 0; j < 8; ++j) { float d = v[j] - mean; vs += d * d; }
#pragma unroll
    for (int off = 32; off; off >>= 1) vs += __shfl_xor(vs, off);
    float rstd = rsqrtf(vs * (1.0f / E) + 1e-5f);
#pragma unroll
    for (int j = 0; j < 8; ++j) {
        int e = j * 64 + lane;
        v[j] = (v[j] - mean) * rstd * g0[e] + b0[e] + cr[e];
    }
    s = 0.f;
#pragma unroll
    for (int j = 0; j < 8; ++j) s += v[j];
#pragma unroll
    for (int off = 32; off; off >>= 1) s += __shfl_xor(s, off);
    mean = s * (1.0f / E);
    vs = 0.f;
#pragma unroll
    for (int j = 0; j < 8; ++j) { float d = v[j] - mean; vs += d * d; }
#pragma unroll
    for (int off = 32; off; off >>= 1) vs += __shfl_xor(vs, off);
    rstd = rsqrtf(vs * (1.0f / E) + 1e-5f);
#pragma unroll
    for (int j = 0; j < 8; ++j) {
        int e = j * 64 + lane;
        v[j] = (v[j] - mean) * rstd * g1[e] + b1[e];
    }
    float h[FF];
#pragma unroll
    for (int f = 0; f < FF; ++f) {
        float p = 0.f;
#pragma unroll
        for (int j = 0; j < 8; ++j) p += v[j] * w1[(size_t)f * E + j * 64 + lane];
#pragma unroll
        for (int off = 32; off; off >>= 1) p += __shfl_xor(p, off);
        h[f] = fmaxf(p + b1f[f], 0.f);
    }
    float o[8];
#pragma unroll
    for (int j = 0; j < 8; ++j) {
        int e = j * 64 + lane;
        float acc = b2f[e];
#pragma unroll
        for (int f4 = 0; f4 < FF / 4; ++f4) {
            float4 w4 = *(const float4*)&w2[(size_t)e * FF + f4 * 4];
            acc += h[f4 * 4 + 0] * w4.x + h[f4 * 4 + 1] * w4.y +
                   h[f4 * 4 + 2] * w4.z + h[f4 * 4 + 3] * w4.w;
        }
        o[j] = v[j] + acc;
    }
    s = 0.f;
#pragma unroll
    for (int j = 0; j < 8; ++j) s += o[j];
#pragma unroll
    for (int off = 32; off; off >>= 1) s += __shfl_xor(s, off);
    mean = s * (1.0f / E);
    vs = 0.f;
#pragma unroll
    for (int j = 0; j < 8; ++j) { float d = o[j] - mean; vs += d * d; }
#pragma unroll
    for (int off = 32; off; off >>= 1) vs += __shfl_xor(vs, off);
    rstd = rsqrtf(vs * (1.0f / E) + 1e-5f);
#pragma unroll
    for (int j = 0; j < 8; ++j) {
        int e = j * 64 + lane;
        const float val = (o[j] - mean) * rstd * g2[e] + bb2[e];
        xout[(size_t)row * E + e] = val;
        if (xbf) {
            __hip_bfloat16 hb = __float2bfloat16(val);
            xbf[(size_t)row * E + e] = *(unsigned short*)&hb;
        }
    }
}

// ------- softmax v3: bf16 logits + exact-fp32 argmax rescue
__global__ __launch_bounds__(1024) void softmax_v3_kernel(
    const float* __restrict__ logits,
    const float* __restrict__ xrow,
    const float* __restrict__ out_w,
    const float* __restrict__ ob,
    float* __restrict__ probs_out, float* __restrict__ tok_out,
    const float* __restrict__ emb, const float* __restrict__ pe_row,
    float* __restrict__ tb_new, int step)
{
    const int b = blockIdx.x, t = threadIdx.x;
    const int wid = t >> 6, lane = t & 63;
    const float* L = logits + (size_t)b * NV;
    float r[32];
    float vmax = -1e30f;
#pragma unroll
    for (int j = 0; j < 32; ++j) {
        const int idx = j * 1024 + t;
        if (idx < NV) { r[j] = L[idx]; vmax = fmaxf(vmax, r[j]); }
        else r[j] = -1e30f;
    }
#pragma unroll
    for (int off = 32; off; off >>= 1) vmax = fmaxf(vmax, __shfl_xor(vmax, off));
    __shared__ float swv[16];
    __shared__ float ssum[16];
    __shared__ float sbc[2];
    __shared__ int scnt;
    __shared__ int cand[64];
    __shared__ float cex[64];
    __shared__ int stok;
    if (lane == 0) swv[wid] = vmax;
    if (t == 0) scnt = 0;
    __syncthreads();
    if (t == 0) {
        float m = swv[0];
        for (int w = 1; w < 16; ++w) m = fmaxf(m, swv[w]);
        sbc[0] = m;
    }
    __syncthreads();
    const float m = sbc[0];
#pragma unroll
    for (int j = 0; j < 32; ++j) {
        const int idx = j * 1024 + t;
        if (idx < NV && r[j] >= m - RESCUE_DELTA) {
            const int p = atomicAdd(&scnt, 1);
            if (p < 64) cand[p] = idx;
        }
    }
    __syncthreads();
    const int nc = min(scnt, 64);
    const float* xr = xrow + (size_t)b * E;
    for (int c = wid; c < nc; c += 16) {
        const float* wr = out_w + (size_t)cand[c] * E;
        const float4 a0 = *(const float4*)&xr[lane * 8];
        const float4 a1 = *(const float4*)&xr[lane * 8 + 4];
        const float4 w0 = *(const float4*)&wr[lane * 8];
        const float4 w1 = *(const float4*)&wr[lane * 8 + 4];
        float s = a0.x * w0.x + a0.y * w0.y + a0.z * w0.z + a0.w * w0.w +
                  a1.x * w1.x + a1.y * w1.y + a1.z * w1.z + a1.w * w1.w;
#pragma unroll
        for (int off = 32; off; off >>= 1) s += __shfl_xor(s, off);
        if (lane == 0) cex[c] = s + ob[cand[c]];
    }
    __syncthreads();
    if (t == 0) {
        float bv = -1e30f; int bi = 0x7fffffff;
        for (int c = 0; c < nc; ++c) {
            const float v = cex[c]; const int ii = cand[c];
            if (v > bv || (v == bv && ii < bi)) { bv = v; bi = ii; }
        }
        stok = bi;
    }
    float psum = 0.f;
#pragma unroll
    for (int j = 0; j < 32; ++j) {
        const int idx = j * 1024 + t;
        if (idx < NV) { r[j] = expf(r[j] - m); psum += r[j]; }
    }
#pragma unroll
    for (int off = 32; off; off >>= 1) psum += __shfl_xor(psum, off);
    if (lane == 0) ssum[wid] = psum;
    __syncthreads();
    if (t == 0) {
        float s = 0.f;
        for (int w = 0; w < 16; ++w) s += ssum[w];
        sbc[1] = 1.0f / s;
    }
    __syncthreads();
    const float inv = sbc[1];
    const int tok = stok;
    float* P = probs_out + (size_t)b * NV;
#pragma unroll
    for (int j = 0; j < 32; ++j) {
        const int idx = j * 1024 + t;
        if (idx < NV) P[idx] = r[j] * inv;
    }
    if (t == 0) tok_out[(size_t)b * NT + step] = (float)tok;
    if (t < E) tb_new[(size_t)b * E + t] = emb[(size_t)tok * E + t] + pe_row[t];
}

// ================================================================ host
extern "C" void kernel_launch(void* const* d_in, const int* in_sizes, int n_in,
                              void* d_out, int out_size, void* d_ws, size_t ws_size,
                              hipStream_t stream) {
    const float* cur_room = (const float*)d_in[0];
    const float* emb      = (const float*)d_in[1];
    const float* sa_in_w  = (const float*)d_in[2];
    const float* sa_in_b  = (const float*)d_in[3];
    const float* sa_out_w = (const float*)d_in[4];
    const float* sa_out_b = (const float*)d_in[5];
    const float* ca_in_w  = (const float*)d_in[6];
    const float* ca_in_b  = (const float*)d_in[7];
    const float* ca_out_w = (const float*)d_in[8];
    const float* ca_out_b = (const float*)d_in[9];
    const float* ff1_w    = (const float*)d_in[10];
    const float* ff1_b    = (const float*)d_in[11];
    const float* ff2_w    = (const float*)d_in[12];
    const float* ff2_b    = (const float*)d_in[13];
    const float* ln_g     = (const float*)d_in[14];
    const float* ln_b     = (const float*)d_in[15];
    const float* out_w    = (const float*)d_in[16];
    const float* out_b    = (const float*)d_in[17];
    float* out = (float*)d_out;

    float* ws = (float*)d_ws;
    float* pe       = ws;
    float* ca_const = pe + 16 * E;
    float* tokb     = ca_const + (size_t)NL * NB * E;
    float* x        = tokb + (size_t)17 * NB * E;
    float* qkv0p    = x + (size_t)NT * NB * E;
    float* qkv0     = qkv0p + (size_t)8 * NB * E3;
    float* qkvp     = qkv0 + (size_t)NT * NB * E3;
    float* attn_o   = qkvp + (size_t)32 * NB * E3;
    float* ypart    = attn_o + (size_t)NT * NB * E;
    float* vocp     = ypart + (size_t)4718592;
    unsigned short* wbf = (unsigned short*)(vocp + (size_t)NB * NV);
    unsigned short* xbf = wbf + (size_t)NV * E;

    setup_kernel<<<144, 256, 0, stream>>>(pe, tokb, emb);
    ca_setup_kernel<<<dim3(NB, NL), 256, 0, stream>>>(
        cur_room, ca_in_w, ca_in_b, ca_out_w, ca_out_b, ca_const);
    cvt_bf16_kernel<<<(NV * E) / 1024, 256, 0, stream>>>(out_w, wbf);

    const size_t QS0 = (size_t)NB * E3;

    for (int i = 0; i < NT; ++i) {
        const int S = i + 1;
        const int M = S * NB;
        const size_t QSM = (size_t)M * E3;
        const size_t YSM = (size_t)M * E;

        // ---- layer 0: incremental qkv (new 128 rows), split-K=8; attn combines
        gemm_v3_kernel<false><<<dim3(E3 / 128, 2, 8), 256, 0, stream>>>(
            tokb + (size_t)i * NB * E, sa_in_w, nullptr, qkv0p, E3, E, 64, QS0, 0);

        const int z_out = (S <= 4) ? 8 : 4;
        for (int l = 0; l < NL; ++l) {
            const float* xin = (l == 0) ? tokb : x;
            const int skipm = (l == 2) ? (S - 1) * NB : 0;
            const int qstart = (l == 2) ? S - 1 : 0;

            if (l == 0) {
                attn_kernel<true><<<NB * NH, 256, 0, stream>>>(
                    qkv0p, QS0, 8, qkv0, qkv0 + (size_t)i * NB * E3,
                    sa_in_b, attn_o, S, 0);
            } else {
                const int z = (S <= 2) ? 8 : (S <= 6) ? 4 : 2;
                gemm_v3_kernel<false><<<dim3(E3 / 128, 2 * S, z), 256, 0, stream>>>(
                    x, sa_in_w + (size_t)l * E3 * E, nullptr, qkvp, E3, E, E / z, QSM, skipm);
                attn_kernel<false><<<NB * NH, 256, 0, stream>>>(
                    qkvp, QSM, z, nullptr, nullptr,
                    sa_in_b + (size_t)l * E3, attn_o, S, qstart);
            }

            if (l == 2) {
                gemm_v3_kernel<false><<<dim3(E / 128, 2, 8), 256, 0, stream>>>(
                    attn_o + (size_t)(S - 1) * NB * E, sa_out_w + (size_t)l * E * E,
                    nullptr, ypart, E, E, 64, (size_t)NB * E, 0);
                epilogue_kernel<<<32, 256, 0, stream>>>(
                    xin + (size_t)(S - 1) * NB * E, ypart, (size_t)NB * E, 8,
                    sa_out_b + (size_t)l * E, ca_const + (size_t)l * NB * E,
                    ln_g + (size_t)(l * 3 + 0) * E, ln_b + (size_t)(l * 3 + 0) * E,
                    ln_g + (size_t)(l * 3 + 1) * E, ln_b + (size_t)(l * 3 + 1) * E,
                    ff1_w + (size_t)l * FF * E, ff1_b + (size_t)l * FF,
                    ff2_w + (size_t)l * E * FF, ff2_b + (size_t)l * E,
                    ln_g + (size_t)(l * 3 + 2) * E, ln_b + (size_t)(l * 3 + 2) * E,
                    x + (size_t)(S - 1) * NB * E, xbf, NB);
            } else {
                gemm_v3_kernel<false><<<dim3(E / 128, 2 * S, z_out), 256, 0, stream>>>(
                    attn_o, sa_out_w + (size_t)l * E * E, nullptr,
                    ypart, E, E, E / z_out, YSM, 0);
                epilogue_kernel<<<S * 32, 256, 0, stream>>>(
                    xin, ypart, YSM, z_out,
                    sa_out_b + (size_t)l * E, ca_const + (size_t)l * NB * E,
                    ln_g + (size_t)(l * 3 + 0) * E, ln_b + (size_t)(l * 3 + 0) * E,
                    ln_g + (size_t)(l * 3 + 1) * E, ln_b + (size_t)(l * 3 + 1) * E,
                    ff1_w + (size_t)l * FF * E, ff1_b + (size_t)l * FF,
                    ff2_w + (size_t)l * E * FF, ff2_b + (size_t)l * E,
                    ln_g + (size_t)(l * 3 + 2) * E, ln_b + (size_t)(l * 3 + 2) * E,
                    x, nullptr, M);
            }
        }
        // ---- vocab: bf16 MFMA logits + softmax with exact-fp32 argmax rescue
        vgemm_bf16_kernel<<<NV / 128, 256, 0, stream>>>(xbf, wbf, out_b, vocp);
        softmax_v3_kernel<<<NB, 1024, 0, stream>>>(
            vocp, x + (size_t)i * NB * E, out_w, out_b,
            out + 2048 + (size_t)i * NB * NV, out,
            emb, pe + (size_t)i * E, tokb + (size_t)S * NB * E, i);
    }
}